// Round 1
// baseline (32.098 us; speedup 1.0000x reference)
//
#include <hip/hip_runtime.h>
#include <math.h>

// ReliabLoss — analytic simplification:
//   P = sqrt(Dm)*W*sqrt(Dm) is ELEMENTWISE -> P = diag(d)  (W[i][i]=1)
//   A = 0.5*(I - 0.5*diag(d)) is diagonal -> Fm = phi / A_ii
//   U = Fm / Fm.rowsum = phi / (TAO + sum(labels_row))   (A_ii cancels exactly)
// => outputs depend only on preds (256x81) and labels (256x80). images unused.

constexpr int NC  = 80;   // nclass
constexpr int BS  = 256;  // batch
constexpr float TAO_C = 0.2f;
constexpr float EPS_C = 1e-5f;

__global__ __launch_bounds__(BS)
void reliab_loss_kernel(const float* __restrict__ preds,
                        const float* __restrict__ labels,
                        float* __restrict__ out) {
    __shared__ float skl[BS];
    __shared__ float srel[BS];
    __shared__ float sirr[BS];
    __shared__ float spos[BS];

    const int i = threadIdx.x;               // one row per thread
    const float* pr = preds  + (size_t)i * (NC + 1);
    const float* lb = labels + (size_t)i * NC;

    // --- softmax denominator (reference: p = exp(preds); p /= p.sum()) ---
    float sum = 0.0f;
    for (int j = 0; j <= NC; ++j) sum += expf(pr[j]);

    // --- label row sum s, ratio r ---
    float s = 0.0f;
    for (int j = 0; j < NC; ++j) s += lb[j];
    const float denom = TAO_C + s;            // phi row sum
    const float r     = s / ((float)NC - s);

    const float p0 = expf(pr[0]) / sum;

    // U[:,0] = TAO/denom ; U[:,j+1] = label_j/denom
    const float u0    = TAO_C / denom;
    const float u1    = 1.0f / denom;
    const float logu1 = logf(u1);

    float kl  = u0 * (logf(u0) - logf(p0 + EPS_C));
    float rel = 0.0f;
    float irr = 0.0f;

    for (int j = 0; j < NC; ++j) {
        const float pj = expf(pr[j + 1]) / sum;
        if (lb[j] == 1.0f) {
            kl  += u1 * (logu1 - logf(pj + EPS_C));
            rel += fmaxf(p0 - pj, 0.0f);
        } else {
            irr += fmaxf(r * (pj - p0), 0.0f);
        }
    }

    skl[i]  = kl;
    srel[i] = rel;
    sirr[i] = irr;
    spos[i] = s;
    __syncthreads();

    // pairwise tree reduction over 256 rows
    for (int off = BS / 2; off > 0; off >>= 1) {
        if (i < off) {
            skl[i]  += skl[i + off];
            srel[i] += srel[i + off];
            sirr[i] += sirr[i + off];
            spos[i] += spos[i + off];
        }
        __syncthreads();
    }

    if (i == 0) {
        const float pos_cnt = spos[0];
        const float neg_cnt = (float)(BS * NC) - pos_cnt;
        const float kl_out  = skl[0] / (float)BS;
        const float emp_rel   = srel[0] / pos_cnt;
        const float emp_irrel = sirr[0] / neg_cnt;
        out[0] = kl_out;
        out[1] = (emp_rel + emp_irrel) * (float)BS;
    }
}

extern "C" void kernel_launch(void* const* d_in, const int* in_sizes, int n_in,
                              void* d_out, int out_size, void* d_ws, size_t ws_size,
                              hipStream_t stream) {
    // d_in[0] = images (unused — mathematically dead, see header comment)
    const float* preds  = (const float*)d_in[1];
    const float* labels = (const float*)d_in[2];
    float* out = (float*)d_out;

    reliab_loss_kernel<<<1, BS, 0, stream>>>(preds, labels, out);
}

// Round 2
// 11.562 us; speedup vs baseline: 2.7761x; 2.7761x over previous
//
#include <hip/hip_runtime.h>
#include <math.h>

// ReliabLoss — analytic simplification (verified R0, absmax 0.0):
//   P = sqrt(Dm)*W*sqrt(Dm) is ELEMENTWISE -> P = diag(d)  (W[i][i]=1)
//   A = 0.5*(I - 0.5*diag(d)) is diagonal -> Fm = phi / A_ii
//   U = Fm / Fm.rowsum = phi / (TAO + sum(labels_row))   (A_ii cancels exactly)
// => outputs depend only on preds (256x81) and labels (256x80). images unused.
//
// R1: latency-bound fix. One wave per row (256 blocks x 64 lanes), lane-parallel
// over the 81 columns + wave shuffle reduce; tiny second kernel folds the 256
// per-row float4 partials. Replaces the R0 single-block serial-chain kernel
// (32 us: ~250 serial transcendentals + 161 gather-loads per thread on 1 CU).

constexpr int NC  = 80;   // nclass
constexpr int BS  = 256;  // batch
constexpr float TAO_C = 0.2f;
constexpr float EPS_C = 1e-5f;

__device__ __forceinline__ float wave_sum(float v) {
    #pragma unroll
    for (int off = 32; off > 0; off >>= 1) v += __shfl_xor(v, off);
    return v;
}

// One wave per row. part[row] = {kl_i, rel_i, irr_i, s_i}
__global__ __launch_bounds__(64)
void reliab_row_kernel(const float* __restrict__ preds,
                       const float* __restrict__ labels,
                       float4* __restrict__ part) {
    const int row = blockIdx.x;
    const int l   = threadIdx.x;                 // lane 0..63
    const float* pr = preds  + (size_t)row * (NC + 1);
    const float* lb = labels + (size_t)row * NC;

    // ---- labels: lane l owns class l, and class l+64 if l<16 ----
    const float lb_a = lb[l];
    const float lb_b = (l < 16) ? lb[l + 64] : 0.0f;
    const float s    = wave_sum(lb_a + lb_b);    // row positive count

    // ---- softmax denom: lane l owns pred col l+1 (and l+65 if l<16); lane0 also col 0 ----
    const float ea = expf(pr[l + 1]);
    const float eb = (l < 16) ? expf(pr[l + 65]) : 0.0f;
    const float e0 = (l == 0) ? expf(pr[0])      : 0.0f;
    const float sum = wave_sum(ea + eb + e0);
    const float inv_sum = 1.0f / sum;

    const float p0 = __shfl(e0, 0) * inv_sum;

    // ---- per-row constants from the analytic solve collapse ----
    const float denom = TAO_C + s;               // phi row sum
    const float r     = s / ((float)NC - s);
    const float u0    = TAO_C / denom;
    const float u1    = 1.0f / denom;
    const float logu1 = logf(u1);

    // ---- per-class terms ----
    float kl = 0.0f, rel = 0.0f, irr = 0.0f;

    const float pa = ea * inv_sum;               // class l
    if (lb_a == 1.0f) {
        kl  += u1 * (logu1 - logf(pa + EPS_C));
        rel += fmaxf(p0 - pa, 0.0f);
    } else {
        irr += fmaxf(r * (pa - p0), 0.0f);
    }
    if (l < 16) {                                // class l+64
        const float pb = eb * inv_sum;
        if (lb_b == 1.0f) {
            kl  += u1 * (logu1 - logf(pb + EPS_C));
            rel += fmaxf(p0 - pb, 0.0f);
        } else {
            irr += fmaxf(r * (pb - p0), 0.0f);
        }
    }
    if (l == 0) {                                // U[:,0] column term
        kl += u0 * (logf(u0) - logf(p0 + EPS_C));
    }

    kl  = wave_sum(kl);
    rel = wave_sum(rel);
    irr = wave_sum(irr);

    if (l == 0) part[row] = make_float4(kl, rel, irr, s);
}

// Fold 256 per-row partials -> out[0..1]
__global__ __launch_bounds__(BS)
void reliab_reduce_kernel(const float4* __restrict__ part,
                          float* __restrict__ out) {
    __shared__ float4 sm[BS];
    const int i = threadIdx.x;
    sm[i] = part[i];
    __syncthreads();
    for (int off = BS / 2; off > 0; off >>= 1) {
        if (i < off) {
            sm[i].x += sm[i + off].x;
            sm[i].y += sm[i + off].y;
            sm[i].z += sm[i + off].z;
            sm[i].w += sm[i + off].w;
        }
        __syncthreads();
    }
    if (i == 0) {
        const float pos_cnt = sm[0].w;
        const float neg_cnt = (float)(BS * NC) - pos_cnt;
        out[0] = sm[0].x / (float)BS;
        out[1] = (sm[0].y / pos_cnt + sm[0].z / neg_cnt) * (float)BS;
    }
}

extern "C" void kernel_launch(void* const* d_in, const int* in_sizes, int n_in,
                              void* d_out, int out_size, void* d_ws, size_t ws_size,
                              hipStream_t stream) {
    // d_in[0] = images (unused — mathematically dead, see header comment)
    const float* preds  = (const float*)d_in[1];
    const float* labels = (const float*)d_in[2];
    float4* part = (float4*)d_ws;                // 256 * 16 B scratch
    float* out = (float*)d_out;

    reliab_row_kernel<<<BS, 64, 0, stream>>>(preds, labels, part);
    reliab_reduce_kernel<<<1, BS, 0, stream>>>(part, out);
}